// Round 1
// 1007.530 us; speedup vs baseline: 1.0436x; 1.0436x over previous
//
#include <hip/hip_runtime.h>
#include <cstdint>

#define BM 128
#define BN 128
#define BK 32

typedef __attribute__((ext_vector_type(8))) short short8;
typedef _Float16 half8 __attribute__((ext_vector_type(8)));
typedef __attribute__((ext_vector_type(4))) float floatx4;

union H8 { short8 s; half8 h; };

static constexpr float SIBS   = 0.044194173824159216f; // 1/sqrt(512)
static constexpr float LS_INV = 1.0f / 2048.0f;

__device__ __forceinline__ unsigned short f2bf(float x){
    union { float f; unsigned u32; } v; v.f = x;
    unsigned r = ((v.u32 >> 16) & 1u) + 0x7fffu;
    return (unsigned short)((v.u32 + r) >> 16);
}
__device__ __forceinline__ void split_f16(float x, unsigned short& h, unsigned short& s){
    _Float16 hh = (_Float16)x;
    _Float16 ss = (_Float16)((x - (float)hh) * 2048.0f);
    union { _Float16 f; unsigned short u; } a, b;
    a.f = hh; b.f = ss;
    h = a.u; s = b.u;
}

#define GLDS(g, l) __builtin_amdgcn_global_load_lds( \
    (const __attribute__((address_space(1))) void*)(g), \
    (__attribute__((address_space(3))) void*)(l), 16, 0, 0)

// ---- prep: fp32 src[R][C] -> transposed fp16 hi/lo-scaled pair [C][R] ----
__global__ void prep_split16_T(const float* __restrict__ src,
                               unsigned short* __restrict__ hiT,
                               unsigned short* __restrict__ lsT,
                               int R, int C)
{
    __shared__ float t[32][33];
    int c0 = blockIdx.x * 32, r0 = blockIdx.y * 32;
    int tx = threadIdx.x & 31, ty = threadIdx.x >> 5;
#pragma unroll
    for (int k = 0; k < 4; k++){
        int r = ty + k*8;
        t[r][tx] = src[(size_t)(r0 + r) * C + c0 + tx];
    }
    __syncthreads();
#pragma unroll
    for (int k = 0; k < 4; k++){
        int r = ty + k*8;
        float x = t[tx][r]; // = src[r0+tx][c0+r]
        unsigned short h, s;
        split_f16(x, h, s);
        size_t o = (size_t)(c0 + r) * R + r0 + tx;
        hiT[o] = h; lsT[o] = s;
    }
}

// ---- prep: Wc2 = WcL + WcR (512x512), transposed fp16 hi/lo pair ----
__global__ void prep_wc2_T(const float* __restrict__ Wc,
                           unsigned short* __restrict__ hiT,
                           unsigned short* __restrict__ lsT)
{
    __shared__ float t[32][33];
    int c0 = blockIdx.x * 32, r0 = blockIdx.y * 32;
    int tx = threadIdx.x & 31, ty = threadIdx.x >> 5;
#pragma unroll
    for (int k = 0; k < 4; k++){
        int r = ty + k*8;
        t[r][tx] = Wc[(size_t)(r0 + r) * 1024 + c0 + tx]
                 + Wc[(size_t)(r0 + r) * 1024 + 512 + c0 + tx];
    }
    __syncthreads();
#pragma unroll
    for (int k = 0; k < 4; k++){
        int r = ty + k*8;
        float x = t[tx][r];
        unsigned short h, s;
        split_f16(x, h, s);
        size_t o = (size_t)(c0 + r) * 512 + r0 + tx;
        hiT[o] = h; lsT[o] = s;
    }
}

// ---- prep: fp32 src[R][C] -> transposed bf16 [C][R] ----
__global__ void prep_bf16_T(const float* __restrict__ src,
                            unsigned short* __restrict__ dstT,
                            int R, int C)
{
    __shared__ float t[32][33];
    int c0 = blockIdx.x * 32, r0 = blockIdx.y * 32;
    int tx = threadIdx.x & 31, ty = threadIdx.x >> 5;
#pragma unroll
    for (int k = 0; k < 4; k++){
        int r = ty + k*8;
        t[r][tx] = src[(size_t)(r0 + r) * C + c0 + tx];
    }
    __syncthreads();
#pragma unroll
    for (int k = 0; k < 4; k++){
        int r = ty + k*8;
        dstT[(size_t)(c0 + r) * R + r0 + tx] = f2bf(t[tx][r]);
    }
}

// ---------------- unified GEMM ----------------
// MODE 0: h0   — A = gathered emb rows (fp32 -> fp16 2-limb in-kernel),
//                writes nodes0 fp32 + hi/lo limb arrays
// MODE 1: tree — A = pre-split limb arrays via GLDS, +bc+sib,
//                writes nodes_next fp32 (+ limbs when DEPTH==0). NO atomics.
// MODE 2: out  — A = pooled (bf16), B = WoutT (bf16), fp32 logits (+bout)
// MODE 3: agg  — A = S limbs, B = Wc2T limbs; epilogue fuses
//                pooled = bf16((h0 + S@Wc2 + m*constv) / cnt)
// B pre-transposed [N][K], K=512. MODE!=2: BTh/BTl fp16 pair; MODE 2: BTh bf16.
template<int MODE, int DEPTH>
__global__ __launch_bounds__(256, 2)
void gemm_k(const unsigned short* __restrict__ Abf,
            const unsigned short* __restrict__ Agh,
            const unsigned short* __restrict__ Agl,
            const unsigned short* __restrict__ BTh,
            const unsigned short* __restrict__ BTl,
            const float* __restrict__ bias,
            const int* __restrict__ tokens,
            const float* __restrict__ emb,
            const float* __restrict__ sib,
            const float* __restrict__ mArr,
            const float* __restrict__ cinv,
            const float* __restrict__ h0,
            float* __restrict__ nodes_next,
            unsigned short* __restrict__ nxh,
            unsigned short* __restrict__ nxl,
            float* __restrict__ f32out,
            unsigned short* __restrict__ pooled,
            float* __restrict__ out,
            int N)
{
    constexpr int K = 512;
    // fragment-contiguous LDS: slot s = kq*128 + m, 8 elems (16B) per slot
    __shared__ __align__(16) unsigned short Ah[BM*BK];
    __shared__ __align__(16) unsigned short Al[BM*BK];
    __shared__ __align__(16) unsigned short Bh[BK*BN];
    __shared__ __align__(16) unsigned short Bl[BK*BN];

    const int tid = threadIdx.x;
    const int w = tid >> 6, l = tid & 63;
    const int wr = w >> 1, wc = w & 1;
    const int row0 = blockIdx.x * BM;
    const int n0   = blockIdx.y * BN;
    const int q = l >> 4, lm = l & 15;

    floatx4 acc[4][4]  = {};
    floatx4 accx[4][4] = {};

    // A-source row pointer (MODE 0: emb gather, split in VGPRs)
    const float* aptr = nullptr;
    const int am = tid & 127, kq0 = tid >> 7;
    if (MODE == 0) aptr = emb + (long)tokens[row0 + am] * K;

    long arow0 = 0, arow1 = 0;
    if (MODE != 0){
        arow0 = (long)(row0 + l) * K;
        arow1 = (long)(row0 + 64 + l) * K;
    }
    const long brow0 = (long)(n0 + l) * K;
    const long brow1 = (long)(n0 + 64 + l) * K;

    for (int k0 = 0; k0 < K; k0 += BK){
        __syncthreads();
        // stage B (hi): wave w covers kq=w, rows l and 64+l
        GLDS(BTh + brow0 + k0 + w*8, (char*)Bh + w*2048);
        GLDS(BTh + brow1 + k0 + w*8, (char*)Bh + w*2048 + 1024);
        if (MODE != 2){
            GLDS(BTl + brow0 + k0 + w*8, (char*)Bl + w*2048);
            GLDS(BTl + brow1 + k0 + w*8, (char*)Bl + w*2048 + 1024);
        }
        if (MODE == 1 || MODE == 3){
            // A pre-split limbs straight to LDS — no VALU split in the loop
            GLDS(Agh + arow0 + k0 + w*8, (char*)Ah + w*2048);
            GLDS(Agh + arow1 + k0 + w*8, (char*)Ah + w*2048 + 1024);
            GLDS(Agl + arow0 + k0 + w*8, (char*)Al + w*2048);
            GLDS(Agl + arow1 + k0 + w*8, (char*)Al + w*2048 + 1024);
        } else if (MODE == 2){
            GLDS(Abf + arow0 + k0 + w*8, (char*)Ah + w*2048);
            GLDS(Abf + arow1 + k0 + w*8, (char*)Ah + w*2048 + 1024);
        } else {
            // MODE 0: fp32 gather -> fp16 hi/lo limbs through VGPRs
#pragma unroll
            for (int t = 0; t < 2; t++){
                int kq = kq0 + 2*t;
                const float* src = aptr + k0 + kq*8;
                float xs[8];
                *(floatx4*)&xs[0] = *(const floatx4*)(src);
                *(floatx4*)&xs[4] = *(const floatx4*)(src + 4);
                unsigned short h8[8], l8[8];
#pragma unroll
                for (int e = 0; e < 8; e++) split_f16(xs[e], h8[e], l8[e]);
                int s = kq*128 + am;
                *(short8*)&Ah[s*8] = *(const short8*)h8;
                *(short8*)&Al[s*8] = *(const short8*)l8;
            }
        }
        __syncthreads();

        H8 bh[4], bl[4];
#pragma unroll
        for (int j = 0; j < 4; j++){
            bh[j].s = *(const short8*)&Bh[(q*128 + wc*64 + j*16 + lm)*8];
            if (MODE != 2)
                bl[j].s = *(const short8*)&Bl[(q*128 + wc*64 + j*16 + lm)*8];
        }
#pragma unroll
        for (int i = 0; i < 4; i++){
            H8 ah; ah.s = *(const short8*)&Ah[(q*128 + wr*64 + i*16 + lm)*8];
            if (MODE != 2){
                H8 al; al.s = *(const short8*)&Al[(q*128 + wr*64 + i*16 + lm)*8];
#pragma unroll
                for (int j = 0; j < 4; j++)
                    acc[i][j]  = __builtin_amdgcn_mfma_f32_16x16x32_f16(ah.h, bh[j].h, acc[i][j], 0, 0, 0);
#pragma unroll
                for (int j = 0; j < 4; j++)
                    accx[i][j] = __builtin_amdgcn_mfma_f32_16x16x32_f16(ah.h, bl[j].h, accx[i][j], 0, 0, 0);
#pragma unroll
                for (int j = 0; j < 4; j++)
                    accx[i][j] = __builtin_amdgcn_mfma_f32_16x16x32_f16(al.h, bh[j].h, accx[i][j], 0, 0, 0);
            } else {
#pragma unroll
                for (int j = 0; j < 4; j++)
                    acc[i][j] = __builtin_amdgcn_mfma_f32_16x16x32_bf16(ah.s, bh[j].s, acc[i][j], 0, 0, 0);
            }
        }
    }

    // epilogue: D[row=(l>>4)*4+r][col=l&15] per 16x16 frag
#pragma unroll
    for (int i = 0; i < 4; i++){
        int rbase = row0 + wr*64 + i*16 + q*4;
#pragma unroll
        for (int j = 0; j < 4; j++){
            int col = n0 + wc*64 + j*16 + lm;
            float badd = 0.f, bsum = 0.f;
            int half = 0, h = 0;
            if (MODE == 0 || MODE == 2) badd = bias[col];
            if (MODE == 1){
                half = col >> 9; h = col & 511;
                badd = bias[col] + SIBS * sib[half*512 + h];
            }
            if (MODE == 3)
                bsum = bias[col] + bias[512 + col] + SIBS * (sib[col] + sib[512 + col]);
#pragma unroll
            for (int r = 0; r < 4; r++){
                int row = rbase + r;
                float v = acc[i][j][r];
                if (MODE != 2) v += accx[i][j][r] * LS_INV;
                if (MODE == 0){
                    v += badd;
                    long o = (long)row*512 + col;
                    f32out[o] = v;
                    unsigned short hh, ss; split_f16(v, hh, ss);
                    nxh[o] = hh; nxl[o] = ss;
                } else if (MODE == 1){
                    v += badd;
                    long o = (long)(2*row + half)*512 + h;
                    nodes_next[o] = v;
                    if (DEPTH == 0){
                        unsigned short hh, ss; split_f16(v, hh, ss);
                        nxh[o] = hh; nxl[o] = ss;
                    }
                } else if (MODE == 3){
                    long o = (long)row*512 + col;
                    float outv = (h0[o] + v + mArr[row]*bsum) * cinv[row];
                    pooled[o] = f2bf(outv);
                } else {
                    out[(long)row*(long)N + col] = v + badd;
                }
            }
        }
    }
}

// ---- gate: x = (node + 0.01*dep_d) . Wg + bg ; expand = (x>0) & active ----
__global__ void gate_k(const float* __restrict__ nodes,
                       const float* __restrict__ Wg,
                       const float* __restrict__ bg,
                       const float* __restrict__ deprow,
                       const unsigned char* __restrict__ eprev,
                       unsigned char* __restrict__ e,
                       int depth)
{
    int row = blockIdx.x * 4 + (threadIdx.x >> 6);
    int l = threadIdx.x & 63;
    const float* nr = nodes + (long)row * 512;
    float s = 0.f;
#pragma unroll
    for (int t = 0; t < 8; t++){
        int h = t*64 + l;
        s += (nr[h] + 0.01f * deprow[h]) * Wg[h];
    }
#pragma unroll
    for (int off = 32; off > 0; off >>= 1) s += __shfl_down(s, off);
    if (l == 0){
        float x = s + bg[0];
        unsigned char a = (depth == 0) ? (unsigned char)1 : eprev[row >> 1];
        e[row] = (unsigned char)((x > 0.f) && a);
    }
}

// ---- masked sum: S[n] = sum over expanded nodes at all depths; m, 1/cnt ----
__global__ void msum_k(const float* __restrict__ nodes0,
                       const float* __restrict__ nodes1,
                       const float* __restrict__ nodes2,
                       const unsigned char* __restrict__ e0,
                       const unsigned char* __restrict__ e1,
                       const unsigned char* __restrict__ e2,
                       unsigned short* __restrict__ Sh,
                       unsigned short* __restrict__ Sl,
                       float* __restrict__ mArr,
                       float* __restrict__ cinv)
{
    int n = blockIdx.x;
    float a0  = (float)e0[n];
    float a10 = (float)e1[2*n],   a11 = (float)e1[2*n+1];
    float a20 = (float)e2[4*n],   a21 = (float)e2[4*n+1];
    float a22 = (float)e2[4*n+2], a23 = (float)e2[4*n+3];
    if (threadIdx.x == 0){
        float m = a0 + a10 + a11 + a20 + a21 + a22 + a23;
        mArr[n] = m;
        cinv[n] = 1.f / (1.f + 2.f * m);
    }
    const float* p0 = nodes0 + (long)n * 512;
    const float* p1 = nodes1 + (long)(2*n) * 512;
    const float* p2 = nodes2 + (long)(4*n) * 512;
    for (int c = threadIdx.x; c < 512; c += 256){
        float s = a0 * p0[c]
                + a10 * p1[c]        + a11 * p1[512 + c]
                + a20 * p2[c]        + a21 * p2[512 + c]
                + a22 * p2[1024 + c] + a23 * p2[1536 + c];
        unsigned short hh, ss; split_f16(s, hh, ss);
        long o = (long)n * 512 + c;
        Sh[o] = hh; Sl[o] = ss;
    }
}

extern "C" void kernel_launch(void* const* d_in, const int* in_sizes, int n_in,
                              void* d_out, int out_size, void* d_ws, size_t ws_size,
                              hipStream_t stream)
{
    const int*   tokens = (const int*)d_in[0];
    const float* emb    = (const float*)d_in[1];
    const float* Wp     = (const float*)d_in[2];
    const float* bp     = (const float*)d_in[3];
    const float* Wc     = (const float*)d_in[4];
    const float* bc     = (const float*)d_in[5];
    const float* Wg     = (const float*)d_in[6];
    const float* bg     = (const float*)d_in[7];
    const float* dep    = (const float*)d_in[8];
    const float* sib    = (const float*)d_in[9];
    const float* Wout   = (const float*)d_in[10];
    const float* bout   = (const float*)d_in[11];

    if (ws_size < ((size_t)48 << 20)) return; // need ~42 MB scratch

    char* w = (char*)d_ws;
    auto alloc = [&](size_t bytes)->char*{
        char* p = w; w += (bytes + 255) & ~(size_t)255; return p;
    };
    unsigned short* WpT_h  = (unsigned short*)alloc((size_t)512*512*2);
    unsigned short* WpT_l  = (unsigned short*)alloc((size_t)512*512*2);
    unsigned short* WcT_h  = (unsigned short*)alloc((size_t)1024*512*2);
    unsigned short* WcT_l  = (unsigned short*)alloc((size_t)1024*512*2);
    unsigned short* Wc2T_h = (unsigned short*)alloc((size_t)512*512*2);
    unsigned short* Wc2T_l = (unsigned short*)alloc((size_t)512*512*2);
    unsigned short* WoutT  = (unsigned short*)alloc((size_t)32000*512*2);
    unsigned short* pooled = (unsigned short*)alloc((size_t)4096*512*2);
    unsigned char*  e0     = (unsigned char*)alloc(4096);
    unsigned char*  e1     = (unsigned char*)alloc(8192);
    unsigned char*  e2     = (unsigned char*)alloc(16384);

    // All node/limb intermediates live inside d_out (500 MiB) — each is fully
    // consumed before the final GEMM overwrites the buffer with logits.
    char* ob = (char*)d_out;
    float*          nodes0 = (float*)(ob + ((size_t) 64 << 20)); //  8.4 MB
    unsigned short* n0h    = (unsigned short*)(ob + ((size_t) 80 << 20)); // 4.2
    unsigned short* n0l    = (unsigned short*)(ob + ((size_t) 88 << 20)); // 4.2
    float*          nodes1 = (float*)(ob + ((size_t) 96 << 20)); // 16.8 MB
    unsigned short* n1h    = (unsigned short*)(ob + ((size_t)128 << 20)); // 8.4
    unsigned short* n1l    = (unsigned short*)(ob + ((size_t)144 << 20)); // 8.4
    float*          nodes2 = (float*)(ob + ((size_t)160 << 20)); // 33.6 MB
    unsigned short* Sh     = (unsigned short*)(ob + ((size_t)200 << 20)); // 4.2
    unsigned short* Sl     = (unsigned short*)(ob + ((size_t)208 << 20)); // 4.2
    float*          mArr   = (float*)(ob + ((size_t)216 << 20)); // 16 KB
    float*          cinvA  = (float*)(ob + ((size_t)217 << 20)); // 16 KB
    float*          out    = (float*)d_out;

    prep_split16_T<<<dim3(16, 16),   256, 0, stream>>>(Wp, WpT_h, WpT_l, 512, 512);
    prep_split16_T<<<dim3(32, 16),   256, 0, stream>>>(Wc, WcT_h, WcT_l, 512, 1024);
    prep_wc2_T    <<<dim3(16, 16),   256, 0, stream>>>(Wc, Wc2T_h, Wc2T_l);
    prep_bf16_T   <<<dim3(1000, 16), 256, 0, stream>>>(Wout, WoutT, 512, 32000);

    // h0 = emb[tok] @ Wp + bp  -> nodes0 fp32 + limb pair
    gemm_k<0,0><<<dim3(32, 4), 256, 0, stream>>>(nullptr, nullptr, nullptr,
        WpT_h, WpT_l, bp, tokens, emb, nullptr, nullptr, nullptr, nullptr,
        nullptr, n0h, n0l, nodes0, nullptr, nullptr, 512);

    gate_k<<<1024, 256, 0, stream>>>(nodes0, Wg, bg, dep + 0, nullptr, e0, 0);

    // depth-0 children -> nodes1 fp32 + limbs (no atomics)
    gemm_k<1,0><<<dim3(32, 8), 256, 0, stream>>>(nullptr, n0h, n0l,
        WcT_h, WcT_l, bc, nullptr, nullptr, sib, nullptr, nullptr, nullptr,
        nodes1, n1h, n1l, nullptr, nullptr, nullptr, 1024);

    gate_k<<<2048, 256, 0, stream>>>(nodes1, Wg, bg, dep + 512, e0, e1, 1);

    // depth-1 children -> nodes2 fp32 only (depth-2 child GEMM eliminated)
    gemm_k<1,1><<<dim3(64, 8), 256, 0, stream>>>(nullptr, n1h, n1l,
        WcT_h, WcT_l, bc, nullptr, nullptr, sib, nullptr, nullptr, nullptr,
        nodes2, nullptr, nullptr, nullptr, nullptr, nullptr, 1024);

    gate_k<<<4096, 256, 0, stream>>>(nodes2, Wg, bg, dep + 1024, e1, e2, 2);

    // S = masked sum of expanded nodes across depths; m, 1/cnt per token
    msum_k<<<4096, 256, 0, stream>>>(nodes0, nodes1, nodes2, e0, e1, e2,
        Sh, Sl, mArr, cinvA);

    // pooled = bf16((h0 + S@Wc2 + m*const) / cnt)
    gemm_k<3,0><<<dim3(32, 4), 256, 0, stream>>>(nullptr, Sh, Sl,
        Wc2T_h, Wc2T_l, bc, nullptr, nullptr, sib, mArr, cinvA, nodes0,
        nullptr, nullptr, nullptr, nullptr, pooled, nullptr, 512);

    // logits = pooled @ Wout + bout (bf16 MFMA, fp32 out)
    gemm_k<2,0><<<dim3(32, 250), 256, 0, stream>>>(pooled, nullptr, nullptr,
        WoutT, nullptr, bout, nullptr, nullptr, nullptr, nullptr, nullptr, nullptr,
        nullptr, nullptr, nullptr, nullptr, nullptr, out, 32000);
}